// Round 7
// baseline (209.982 us; speedup 1.0000x reference)
//
#include <hip/hip_runtime.h>
#include <hip/hip_bf16.h>
#include <math.h>

#define NB 128   // batch
#define NR 36    // regions
#define NW 32    // words
#define ND 256   // feature dim

#define MARGINf 0.05f
#define TEMPf   14.0f
#define LAMf    9.0f
#define EPSf    1e-8f
#define LOG2Ef  1.4426950408889634f
#define INV_LOG2Ef 0.6931471805599453f

typedef _Float16 f16x8 __attribute__((ext_vector_type(8)));
typedef _Float16 f16x4 __attribute__((ext_vector_type(4)));
typedef float    f32x4 __attribute__((ext_vector_type(4)));

// ================= workspace layout (float offsets) =================
// All GEMM operands stored in MFMA-fragment order ("swizzled"):
//   fragment f, lane l, elem j  ->  base + f*512 + l*8 + j   (halves)
// so a wave's f16x8 fragment load = 64 lanes x 16B contiguous = 1KB burst.
#define WS_SCORES 0
#define WS_N1     16384
#define WS_GW     20480                   // f16[128][6*512]   (rt*2+ks frags)
#define GW_H      3072
#define WS_IMW    217088                  // f16[128][24*512]  (mt*8+ks frags)
#define IMW_H     12288
#define WS_SHW    1003520                 // f16[128][16*512]  (nt*8+ks frags)
#define SHW_H     8192
#define WS_CNT    2052096                 // u32 block-completion counter
#define NBLK      (32 * NB)               // wavefused grid size

// =====================================================================
// prep5: split into im-side blocks (b < NB) and s-side blocks (b >= NB).
//   im-side: load im -> LDS, build imw fragments (global + LDS copy),
//            Gram via MFMA on the fragments, then swizzled Gw write.
//   s-side:  shw word-masked fragments + n1 (independent of im).
// grid = 2*NB so both halves run concurrently across all 256 CUs.
// Also zeroes the wavefused completion counter (same-stream ordering
// guarantees visibility before wavefused starts).
// =====================================================================
__global__ __launch_bounds__(256) void prep5_kernel(
    const float* __restrict__ im, const float* __restrict__ s,
    const int* __restrict__ s_l, float* __restrict__ ws)
{
    const int t = threadIdx.x;
    const int bid = blockIdx.x;

    __shared__ __align__(16) float    s_imf[NR * 260];
    __shared__ __align__(16) _Float16 s_frag[24 * 512];   // imw fragments, 24KB
    __shared__ __align__(16) _Float16 s_G[48 * 72];

    if (bid == 0 && t == 0) ((unsigned int*)(ws + WS_CNT))[0] = 0u;

    if (bid < NB) {
        // ================= im-side =================
        const int b = bid;
        const float4* im4 = (const float4*)(im + (size_t)b * NR * ND);
        for (int i = t; i < NR * 64; i += 256) {
            int r = i >> 6, c4 = i & 63;
            *(float4*)&s_imf[r * 260 + 4 * c4] = im4[i];
        }
        // zero G LDS (1728 u32) — MFMA only fills cols 0..47; pad stays 0
        for (int i = t; i < 1728; i += 256) ((unsigned int*)s_G)[i] = 0u;
        __syncthreads();

        // imw swizzled: 24 fragments (mt*8+ks) x 64 lanes, rows >=36 zero.
        // Write to global AND stage in LDS for the Gram MFMA.
        _Float16* imw = (_Float16*)(ws + WS_IMW) + (size_t)b * IMW_H;
        for (int i = t; i < 24 * 64; i += 256) {
            const int f = i >> 6, l = i & 63;
            const int mt = f >> 3, ks = f & 7;
            const int lmi = l & 15, kgi = l >> 4;
            const int r = mt * 16 + lmi;
            f16x8 h;
            if (r < NR) {
                const int k0 = ks * 32 + kgi * 8;
                const float4 a  = *(const float4*)&s_imf[r * 260 + k0];
                const float4 bb = *(const float4*)&s_imf[r * 260 + k0 + 4];
                h[0] = (_Float16)a.x;  h[1] = (_Float16)a.y;
                h[2] = (_Float16)a.z;  h[3] = (_Float16)a.w;
                h[4] = (_Float16)bb.x; h[5] = (_Float16)bb.y;
                h[6] = (_Float16)bb.z; h[7] = (_Float16)bb.w;
            } else {
#pragma unroll
                for (int k = 0; k < 8; ++k) h[k] = (_Float16)0.f;
            }
            *(f16x8*)(imw + f * 512 + l * 8) = h;
            *(f16x8*)(s_frag + f * 512 + l * 8) = h;
        }
        __syncthreads();

        // Gram via MFMA: G[i][j] = im[i].im[j], tiles (ta,tb) in 16x16,
        // K=256 over 8 fragment k-slices. Pair p = ta*3+tb, 9 pairs over
        // 4 waves. mfma(rowfragA, rowfragB) -> C[i=kg*4+v][j=lm] = A_i . B_j.
        {
            const int wv = t >> 6, lane = t & 63;
            const int lmi = lane & 15, kgi = lane >> 4;
            for (int p = wv; p < 9; p += 4) {
                const int ta = p / 3, tb = p - ta * 3;
                f32x4 acc = (f32x4){0.f, 0.f, 0.f, 0.f};
#pragma unroll
                for (int ks = 0; ks < 8; ++ks) {
                    f16x8 a  = *(const f16x8*)(s_frag + (ta * 8 + ks) * 512 + lane * 8);
                    f16x8 bb = *(const f16x8*)(s_frag + (tb * 8 + ks) * 512 + lane * 8);
                    acc = __builtin_amdgcn_mfma_f32_16x16x32_f16(a, bb, acc, 0, 0, 0);
                }
#pragma unroll
                for (int v = 0; v < 4; ++v) {
                    const int row = ta * 16 + kgi * 4 + v;
                    s_G[row * 72 + tb * 16 + lmi] = (_Float16)acc[v];
                }
            }
        }
        __syncthreads();

        // Gw swizzled: 6 fragments (rt*2+ks) x 64 lanes
        _Float16* Gw = (_Float16*)(ws + WS_GW) + (size_t)b * GW_H;
        for (int i = t; i < 6 * 64; i += 256) {
            const int f = i >> 6, l = i & 63;
            const int rt = f >> 1, ks = f & 1;
            const int lmi = l & 15, kgi = l >> 4;
            f16x8 h = *(const f16x8*)&s_G[(rt * 16 + lmi) * 72 + ks * 32 + kgi * 8];
            *(f16x8*)((_Float16*)Gw + f * 512 + l * 8) = h;
        }
    } else {
        // ================= s-side =================
        const int b = bid - NB;
        const int sl = s_l[b];
        _Float16* shw = (_Float16*)(ws + WS_SHW) + (size_t)b * SHW_H;
        const float4* s4 = (const float4*)(s + (size_t)b * NW * ND);

        // shw swizzled: 16 fragments (nt*8+ks) x 64 lanes, word-masked
        for (int i = t; i < 16 * 64; i += 256) {
            const int f = i >> 6, l = i & 63;
            const int nt = f >> 3, ks = f & 7;
            const int lmi = l & 15, kgi = l >> 4;
            const int w = nt * 16 + lmi;
            f16x8 h;
            if (w < sl) {
                const int k0 = ks * 32 + kgi * 8;     // multiple of 8 floats
                const float4 a  = s4[w * 64 + (k0 >> 2)];
                const float4 bb = s4[w * 64 + (k0 >> 2) + 1];
                h[0] = (_Float16)a.x;  h[1] = (_Float16)a.y;
                h[2] = (_Float16)a.z;  h[3] = (_Float16)a.w;
                h[4] = (_Float16)bb.x; h[5] = (_Float16)bb.y;
                h[6] = (_Float16)bb.z; h[7] = (_Float16)bb.w;
            } else {
#pragma unroll
                for (int k = 0; k < 8; ++k) h[k] = (_Float16)0.f;
            }
            *(f16x8*)(shw + f * 512 + l * 8) = h;
        }

        // n1[b][w]
        {
            const int w = t >> 3, g = t & 7;
            float acc = 0.f;
            for (int j = 0; j < 8; ++j) {
                float4 v = s4[w * 64 + g * 8 + j];
                acc += v.x * v.x + v.y * v.y + v.z * v.z + v.w * v.w;
            }
            acc += __shfl_down(acc, 4, 8);
            acc += __shfl_down(acc, 2, 8);
            acc += __shfl_down(acc, 1, 8);
            if (g == 0) ws[WS_N1 + b * NW + w] = sqrtf(acc);
        }
    }
}

// =====================================================================
// wavefused10: byte-exact R2 wavefused5 body (the measured-best: ONE
// WAVE per (b,c), straight-line, zero barriers, (256,4), B 2-deep dbuf,
// A 2-deep dbuf, raw v_exp/v_sqrt/v_rcp) + fused contrastive-loss tail:
// the LAST block (device-scope counter) computes the 128-row loss,
// deleting the separate 1-block loss_kernel launch (~4-6us serial).
// R3-R6 lesson: every structural change to the body regressed; the body
// is VALU-issue-bound at its register-pinned occupancy. Tail code is
// register-dead w.r.t. the body (allocator splits), so no perturbation.
// =====================================================================
__global__ __launch_bounds__(256, 4) void wavefused10_kernel(
    const int* __restrict__ s_l, const float* __restrict__ im_mask,
    const int* __restrict__ qid, float* __restrict__ ws,
    float* __restrict__ out)
{
    const int t = threadIdx.x;
    const int wv = t >> 6, lane = t & 63;
    const int lm = lane & 15, kg = lane >> 4;
    const int b = blockIdx.y;
    const int c = blockIdx.x * 4 + wv;

    __shared__ _Float16 sE[4][32 * 72];   // per-wave E tile [w][k], 4.6 KB each

    const _Float16* aB = (const _Float16*)(ws + WS_IMW) + (size_t)b * IMW_H + lane * 8;
    const _Float16* bB = (const _Float16*)(ws + WS_SHW) + (size_t)c * SHW_H + lane * 8;
    const _Float16* gB = (const _Float16*)(ws + WS_GW) + (size_t)b * GW_H + lane * 8;

    // early small loads (L1/L2-resident, broadcast-friendly)
    float n1v[2];
#pragma unroll
    for (int nt = 0; nt < 2; ++nt)
        n1v[nt] = ws[WS_N1 + c * NW + nt * 16 + lm];
    float mr[12];
#pragma unroll
    for (int mt = 0; mt < 3; ++mt)
#pragma unroll
        for (int v = 0; v < 4; ++v) {
            const int r = mt * 16 + kg * 4 + v;
            mr[mt * 4 + v] = (r < NR) ? im_mask[b * NR + r] : 0.f;
        }
    const int sl = s_l[c];

    // accumulator array, aliased:
    //   phase 1: accv[mt*2+nt] = A0 raw tile
    //   n2 MFMA: accv[rt*2+wt] = D tile (raw dead by then)
    f32x4 accv[6];
#pragma unroll
    for (int i = 0; i < 6; ++i) accv[i] = (f32x4){0.f, 0.f, 0.f, 0.f};

    // ---- phase 1: A0 tile 48(r) x 32(w), K=256, coalesced frag loads ----
    f16x8 af[2][3], bf[2][2];
#pragma unroll
    for (int mt = 0; mt < 3; ++mt) af[0][mt] = *(const f16x8*)(aB + (mt * 8 + 0) * 512);
#pragma unroll
    for (int nt = 0; nt < 2; ++nt) bf[0][nt] = *(const f16x8*)(bB + (nt * 8 + 0) * 512);

#pragma unroll
    for (int ks = 0; ks < 8; ++ks) {
        const int cur = ks & 1, nxt = cur ^ 1;
        if (ks < 7) {
#pragma unroll
            for (int mt = 0; mt < 3; ++mt)
                af[nxt][mt] = *(const f16x8*)(aB + (mt * 8 + ks + 1) * 512);
#pragma unroll
            for (int nt = 0; nt < 2; ++nt)
                bf[nxt][nt] = *(const f16x8*)(bB + (nt * 8 + ks + 1) * 512);
        }
#pragma unroll
        for (int mt = 0; mt < 3; ++mt)
#pragma unroll
            for (int nt = 0; nt < 2; ++nt)
                accv[mt * 2 + nt] = __builtin_amdgcn_mfma_f32_16x16x32_f16(af[cur][mt], bf[cur][nt], accv[mt * 2 + nt], 0, 0, 0);
    }
    // lane holds raw[r][w]: r = mt*16 + kg*4 + v, w = nt*16 + lm

    // ---- norm over w -> coef[r]; X cached in er[] for the exp pass ----
    f32x4 er[6];
    float coef[12];
#pragma unroll
    for (int mt = 0; mt < 3; ++mt)
#pragma unroll
        for (int v = 0; v < 4; ++v) {
            const int idx = mt * 4 + v;
            const float one_m = 1.f - mr[idx];
            float p = 0.f;
#pragma unroll
            for (int nt = 0; nt < 2; ++nt) {
                const float raw = accv[mt * 2 + nt][v];
                const float X = fmaxf(raw, 0.1f * raw) + one_m;   // leaky+pad
                er[mt * 2 + nt][v] = X;
                p += X * X;
            }
            p += __shfl_xor(p, 1);
            p += __shfl_xor(p, 2);
            p += __shfl_xor(p, 4);
            p += __shfl_xor(p, 8);
            coef[idx] = (LAMf * LOG2Ef) *
                        __builtin_amdgcn_rcpf(__builtin_amdgcn_sqrtf(p) + EPSf);
        }

    // ---- E = exp2(X*coef)*m; keep E in f32 regs AND LDS [w][72] f16 ----
    _Float16* sEw = &sE[wv][0];
    float den[2] = {0.f, 0.f}, Wv[2] = {0.f, 0.f};
#pragma unroll
    for (int nt = 0; nt < 2; ++nt) {
        const int w = nt * 16 + lm;
#pragma unroll
        for (int mt = 0; mt < 3; ++mt) {
            f16x4 pk;
#pragma unroll
            for (int v = 0; v < 4; ++v) {
                const int idx = mt * 4 + v;
                const float raw = accv[mt * 2 + nt][v];
                const float X   = er[mt * 2 + nt][v];
                const float E = __builtin_amdgcn_exp2f(X * coef[idx]) * mr[idx];
                er[mt * 2 + nt][v] = E;
                den[nt] += E;
                Wv[nt] += E * raw;
                pk[v] = (_Float16)E;
            }
            *(f16x4*)&sEw[w * 72 + mt * 16 + kg * 4] = pk;
        }
        // zero K-pad k = 48..63 (G kills it numerically, avoid stray NaN bits)
        f16x4 z4; z4[0] = z4[1] = z4[2] = z4[3] = (_Float16)0.f;
        *(f16x4*)&sEw[w * 72 + 48 + kg * 4] = z4;
    }
    // reduce den/W over kg (rows split across kg)
#pragma unroll
    for (int nt = 0; nt < 2; ++nt) {
        den[nt] += __shfl_xor(den[nt], 16);
        den[nt] += __shfl_xor(den[nt], 32);
        Wv[nt]  += __shfl_xor(Wv[nt], 16);
        Wv[nt]  += __shfl_xor(Wv[nt], 32);
    }

    // ---- n2: D = G(48x48) * E(48x32) -> C-layout aligned with er ----
    // accv reused as D (raw fully consumed above)
#pragma unroll
    for (int i = 0; i < 6; ++i) accv[i] = (f32x4){0.f, 0.f, 0.f, 0.f};
#pragma unroll
    for (int ks = 0; ks < 2; ++ks) {
        f16x8 ef[2], gf[3];
#pragma unroll
        for (int wt = 0; wt < 2; ++wt)
            ef[wt] = *(const f16x8*)&sEw[(wt * 16 + lm) * 72 + ks * 32 + kg * 8];
#pragma unroll
        for (int rt = 0; rt < 3; ++rt)
            gf[rt] = *(const f16x8*)(gB + (rt * 2 + ks) * 512);
#pragma unroll
        for (int rt = 0; rt < 3; ++rt)
#pragma unroll
            for (int wt = 0; wt < 2; ++wt)
                accv[rt * 2 + wt] = __builtin_amdgcn_mfma_f32_16x16x32_f16(gf[rt], ef[wt], accv[rt * 2 + wt], 0, 0, 0);
    }
    // n2[w] = sum_r D[r][w]*E[r][w]: pure register dot + kg reduction
    float n2v[2];
#pragma unroll
    for (int nt = 0; nt < 2; ++nt) {
        float p2 = 0.f;
#pragma unroll
        for (int rt = 0; rt < 3; ++rt)
#pragma unroll
            for (int v = 0; v < 4; ++v)
                p2 += accv[rt * 2 + nt][v] * er[rt * 2 + nt][v];
        p2 += __shfl_xor(p2, 16);
        p2 += __shfl_xor(p2, 32);
        n2v[nt] = p2;
    }

    // ---- final: cos (softmax denominators cancel), sum over words ----
    {
        float tot = 0.f;
#pragma unroll
        for (int nt = 0; nt < 2; ++nt) {
            const int w = nt * 16 + lm;
            const float n2 = fmaxf(n2v[nt], 0.f);
            const float denom = fmaxf(n1v[nt] * __builtin_amdgcn_sqrtf(n2), EPSf * den[nt]);
            const float cosv = Wv[nt] * __builtin_amdgcn_rcpf(denom);
            tot += (w < sl) ? cosv : 0.f;
        }
        tot += __shfl_xor(tot, 1);
        tot += __shfl_xor(tot, 2);
        tot += __shfl_xor(tot, 4);
        tot += __shfl_xor(tot, 8);
        if (lane == 0) ws[WS_SCORES + b * NB + c] = tot * __builtin_amdgcn_rcpf((float)sl);
    }

    // ================== fused loss tail (last block only) ==================
    __shared__ int s_last;
    __syncthreads();                       // all 4 waves' score stores issued+drained
    if (t == 0) {
        __threadfence();                   // L2 writeback: scores device-visible
        unsigned old = atomicAdd((unsigned int*)(ws + WS_CNT), 1u);
        s_last = (old == (unsigned)(NBLK - 1)) ? 1 : 0;
    }
    __syncthreads();
    if (!s_last) return;
    __threadfence();                       // acquire: invalidate stale cache

    const float* scores = ws + WS_SCORES;
    __shared__ int   s_q[NB];
    __shared__ float s_ra[4];
    __shared__ float s_rv[4];
    if (t < NB) s_q[t] = qid[t];
    __syncthreads();

    float a = 0.f, vcnt = 0.f;
    if (t < NB) {
        const int q = s_q[t];
        bool dup = false;
        for (int j = 0; j < t; ++j) dup = dup || (s_q[j] == q);
        const float* row = scores + t * NB;
        float mx = -1e30f;
        for (int j = 0; j < NB; ++j) {
            float l = (row[j] - ((j == t) ? MARGINf : 0.f)) * TEMPf;
            mx = fmaxf(mx, l);
        }
        float sum = 0.f;
        for (int j = 0; j < NB; ++j) {
            float l = (row[j] - ((j == t) ? MARGINf : 0.f)) * TEMPf;
            sum += __builtin_amdgcn_exp2f((l - mx) * LOG2Ef);
        }
        const float logZ = mx + __builtin_amdgcn_logf(sum) * INV_LOG2Ef;
        const float picked = (row[t] - MARGINf) * TEMPf;
        const float valid = dup ? 0.f : 1.f;
        a = (logZ - picked) * valid;
        vcnt = valid;
    }
    // wave reduction (threads >=128 contribute 0), combine 4 waves via LDS
    a += __shfl_xor(a, 1);  vcnt += __shfl_xor(vcnt, 1);
    a += __shfl_xor(a, 2);  vcnt += __shfl_xor(vcnt, 2);
    a += __shfl_xor(a, 4);  vcnt += __shfl_xor(vcnt, 4);
    a += __shfl_xor(a, 8);  vcnt += __shfl_xor(vcnt, 8);
    a += __shfl_xor(a, 16); vcnt += __shfl_xor(vcnt, 16);
    a += __shfl_xor(a, 32); vcnt += __shfl_xor(vcnt, 32);
    if (lane == 0) { s_ra[wv] = a; s_rv[wv] = vcnt; }
    __syncthreads();
    if (t == 0)
        out[0] = (s_ra[0] + s_ra[1] + s_ra[2] + s_ra[3]) /
                 fmaxf(s_rv[0] + s_rv[1] + s_rv[2] + s_rv[3], 1.f);
}

extern "C" void kernel_launch(void* const* d_in, const int* in_sizes, int n_in,
                              void* d_out, int out_size, void* d_ws, size_t ws_size,
                              hipStream_t stream) {
    const float* im      = (const float*)d_in[0];
    const float* s       = (const float*)d_in[1];
    const int*   s_l     = (const int*)d_in[2];
    const float* im_mask = (const float*)d_in[3];
    const int*   qid     = (const int*)d_in[4];

    float* ws  = (float*)d_ws;
    float* out = (float*)d_out;

    prep5_kernel<<<2 * NB, 256, 0, stream>>>(im, s, s_l, ws);
    wavefused10_kernel<<<dim3(32, NB), 256, 0, stream>>>(s_l, im_mask, qid, ws, out);
}

// Round 8
// 128.692 us; speedup vs baseline: 1.6317x; 1.6317x over previous
//
#include <hip/hip_runtime.h>
#include <hip/hip_bf16.h>
#include <math.h>

#define NB 128   // batch
#define NR 36    // regions
#define NW 32    // words
#define ND 256   // feature dim

#define MARGINf 0.05f
#define TEMPf   14.0f
#define LAMf    9.0f
#define EPSf    1e-8f
#define LOG2Ef  1.4426950408889634f
#define INV_LOG2Ef 0.6931471805599453f

typedef _Float16 f16x8 __attribute__((ext_vector_type(8)));
typedef _Float16 f16x4 __attribute__((ext_vector_type(4)));
typedef float    f32x4 __attribute__((ext_vector_type(4)));

// ================= workspace layout (float offsets) =================
// All GEMM operands stored in MFMA-fragment order ("swizzled"):
//   fragment f, lane l, elem j  ->  base + f*512 + l*8 + j   (halves)
// so a wave's f16x8 fragment load = 64 lanes x 16B contiguous = 1KB burst.
#define WS_SCORES 0
#define WS_N1     16384
#define WS_GW     20480                   // f16[128][6*512]   (rt*2+ks frags)
#define GW_H      3072
#define WS_IMW    217088                  // f16[128][24*512]  (mt*8+ks frags)
#define IMW_H     12288
#define WS_SHW    1003520                 // f16[128][16*512]  (nt*8+ks frags)
#define SHW_H     8192

// =====================================================================
// prep5: split into im-side blocks (b < NB) and s-side blocks (b >= NB).
//   im-side: load im -> LDS, build imw fragments (global + LDS copy),
//            Gram via MFMA on the fragments, then swizzled Gw write.
//   s-side:  shw word-masked fragments + n1 (independent of im).
// grid = 2*NB so both halves run concurrently across all 256 CUs.
// =====================================================================
__global__ __launch_bounds__(256) void prep5_kernel(
    const float* __restrict__ im, const float* __restrict__ s,
    const int* __restrict__ s_l, float* __restrict__ ws)
{
    const int t = threadIdx.x;
    const int bid = blockIdx.x;

    __shared__ __align__(16) float    s_imf[NR * 260];
    __shared__ __align__(16) _Float16 s_frag[24 * 512];   // imw fragments, 24KB
    __shared__ __align__(16) _Float16 s_G[48 * 72];

    if (bid < NB) {
        // ================= im-side =================
        const int b = bid;
        const float4* im4 = (const float4*)(im + (size_t)b * NR * ND);
        for (int i = t; i < NR * 64; i += 256) {
            int r = i >> 6, c4 = i & 63;
            *(float4*)&s_imf[r * 260 + 4 * c4] = im4[i];
        }
        // zero G LDS (1728 u32) — MFMA only fills cols 0..47; pad stays 0
        for (int i = t; i < 1728; i += 256) ((unsigned int*)s_G)[i] = 0u;
        __syncthreads();

        // imw swizzled: 24 fragments (mt*8+ks) x 64 lanes, rows >=36 zero.
        // Write to global AND stage in LDS for the Gram MFMA.
        _Float16* imw = (_Float16*)(ws + WS_IMW) + (size_t)b * IMW_H;
        for (int i = t; i < 24 * 64; i += 256) {
            const int f = i >> 6, l = i & 63;
            const int mt = f >> 3, ks = f & 7;
            const int lmi = l & 15, kgi = l >> 4;
            const int r = mt * 16 + lmi;
            f16x8 h;
            if (r < NR) {
                const int k0 = ks * 32 + kgi * 8;
                const float4 a  = *(const float4*)&s_imf[r * 260 + k0];
                const float4 bb = *(const float4*)&s_imf[r * 260 + k0 + 4];
                h[0] = (_Float16)a.x;  h[1] = (_Float16)a.y;
                h[2] = (_Float16)a.z;  h[3] = (_Float16)a.w;
                h[4] = (_Float16)bb.x; h[5] = (_Float16)bb.y;
                h[6] = (_Float16)bb.z; h[7] = (_Float16)bb.w;
            } else {
#pragma unroll
                for (int k = 0; k < 8; ++k) h[k] = (_Float16)0.f;
            }
            *(f16x8*)(imw + f * 512 + l * 8) = h;
            *(f16x8*)(s_frag + f * 512 + l * 8) = h;
        }
        __syncthreads();

        // Gram via MFMA: G[i][j] = im[i].im[j], tiles (ta,tb) in 16x16,
        // K=256 over 8 fragment k-slices. Pair p = ta*3+tb, 9 pairs over
        // 4 waves. mfma(rowfragA, rowfragB) -> C[i=kg*4+v][j=lm] = A_i . B_j.
        {
            const int wv = t >> 6, lane = t & 63;
            const int lmi = lane & 15, kgi = lane >> 4;
            for (int p = wv; p < 9; p += 4) {
                const int ta = p / 3, tb = p - ta * 3;
                f32x4 acc = (f32x4){0.f, 0.f, 0.f, 0.f};
#pragma unroll
                for (int ks = 0; ks < 8; ++ks) {
                    f16x8 a  = *(const f16x8*)(s_frag + (ta * 8 + ks) * 512 + lane * 8);
                    f16x8 bb = *(const f16x8*)(s_frag + (tb * 8 + ks) * 512 + lane * 8);
                    acc = __builtin_amdgcn_mfma_f32_16x16x32_f16(a, bb, acc, 0, 0, 0);
                }
#pragma unroll
                for (int v = 0; v < 4; ++v) {
                    const int row = ta * 16 + kgi * 4 + v;
                    s_G[row * 72 + tb * 16 + lmi] = (_Float16)acc[v];
                }
            }
        }
        __syncthreads();

        // Gw swizzled: 6 fragments (rt*2+ks) x 64 lanes
        _Float16* Gw = (_Float16*)(ws + WS_GW) + (size_t)b * GW_H;
        for (int i = t; i < 6 * 64; i += 256) {
            const int f = i >> 6, l = i & 63;
            const int rt = f >> 1, ks = f & 1;
            const int lmi = l & 15, kgi = l >> 4;
            f16x8 h = *(const f16x8*)&s_G[(rt * 16 + lmi) * 72 + ks * 32 + kgi * 8];
            *(f16x8*)((_Float16*)Gw + f * 512 + l * 8) = h;
        }
    } else {
        // ================= s-side =================
        const int b = bid - NB;
        const int sl = s_l[b];
        _Float16* shw = (_Float16*)(ws + WS_SHW) + (size_t)b * SHW_H;
        const float4* s4 = (const float4*)(s + (size_t)b * NW * ND);

        // shw swizzled: 16 fragments (nt*8+ks) x 64 lanes, word-masked
        for (int i = t; i < 16 * 64; i += 256) {
            const int f = i >> 6, l = i & 63;
            const int nt = f >> 3, ks = f & 7;
            const int lmi = l & 15, kgi = l >> 4;
            const int w = nt * 16 + lmi;
            f16x8 h;
            if (w < sl) {
                const int k0 = ks * 32 + kgi * 8;     // multiple of 8 floats
                const float4 a  = s4[w * 64 + (k0 >> 2)];
                const float4 bb = s4[w * 64 + (k0 >> 2) + 1];
                h[0] = (_Float16)a.x;  h[1] = (_Float16)a.y;
                h[2] = (_Float16)a.z;  h[3] = (_Float16)a.w;
                h[4] = (_Float16)bb.x; h[5] = (_Float16)bb.y;
                h[6] = (_Float16)bb.z; h[7] = (_Float16)bb.w;
            } else {
#pragma unroll
                for (int k = 0; k < 8; ++k) h[k] = (_Float16)0.f;
            }
            *(f16x8*)(shw + f * 512 + l * 8) = h;
        }

        // n1[b][w]
        {
            const int w = t >> 3, g = t & 7;
            float acc = 0.f;
            for (int j = 0; j < 8; ++j) {
                float4 v = s4[w * 64 + g * 8 + j];
                acc += v.x * v.x + v.y * v.y + v.z * v.z + v.w * v.w;
            }
            acc += __shfl_down(acc, 4, 8);
            acc += __shfl_down(acc, 2, 8);
            acc += __shfl_down(acc, 1, 8);
            if (g == 0) ws[WS_N1 + b * NW + w] = sqrtf(acc);
        }
    }
}

// =====================================================================
// wavefused11: BYTE-EXACT R2 wavefused5 body; single change:
// __launch_bounds__(256, 4) -> (256, 3).
// Rationale: at (256,4) the allocator reported only 48 arch-VGPRs for a
// kernel with ~100 f32 of live array state -> accv/er/af/bf live in
// AGPRs, and every epilogue element access pays v_accvgpr_read/write.
// The kernel is VALU-ISSUE-bound (R1 arithmetic: 4 waves/SIMD x ~2200
// issues x 2cyc x 4 passes ~= the observed 33us), so those ~1000 moves
// are ~40% of runtime. (256,3) caps at ~170 regs: arrays stay in
// arch-VGPRs, occupancy drops 4->3 waves/SIMD (cheap when issue-bound).
// R6 tested (256,3) ONLY together with a 64-reg B-prefetch array; this
// is the single-variable version.
// =====================================================================
__global__ __launch_bounds__(256, 3) void wavefused11_kernel(
    const int* __restrict__ s_l, const float* __restrict__ im_mask,
    float* __restrict__ ws)
{
    const int t = threadIdx.x;
    const int wv = t >> 6, lane = t & 63;
    const int lm = lane & 15, kg = lane >> 4;
    const int b = blockIdx.y;
    const int c = blockIdx.x * 4 + wv;

    __shared__ _Float16 sE[4][32 * 72];   // per-wave E tile [w][k], 4.6 KB each

    const _Float16* aB = (const _Float16*)(ws + WS_IMW) + (size_t)b * IMW_H + lane * 8;
    const _Float16* bB = (const _Float16*)(ws + WS_SHW) + (size_t)c * SHW_H + lane * 8;
    const _Float16* gB = (const _Float16*)(ws + WS_GW) + (size_t)b * GW_H + lane * 8;

    // early small loads (L1/L2-resident, broadcast-friendly)
    float n1v[2];
#pragma unroll
    for (int nt = 0; nt < 2; ++nt)
        n1v[nt] = ws[WS_N1 + c * NW + nt * 16 + lm];
    float mr[12];
#pragma unroll
    for (int mt = 0; mt < 3; ++mt)
#pragma unroll
        for (int v = 0; v < 4; ++v) {
            const int r = mt * 16 + kg * 4 + v;
            mr[mt * 4 + v] = (r < NR) ? im_mask[b * NR + r] : 0.f;
        }
    const int sl = s_l[c];

    // accumulator array, aliased:
    //   phase 1: accv[mt*2+nt] = A0 raw tile
    //   n2 MFMA: accv[rt*2+wt] = D tile (raw dead by then)
    f32x4 accv[6];
#pragma unroll
    for (int i = 0; i < 6; ++i) accv[i] = (f32x4){0.f, 0.f, 0.f, 0.f};

    // ---- phase 1: A0 tile 48(r) x 32(w), K=256, coalesced frag loads ----
    f16x8 af[2][3], bf[2][2];
#pragma unroll
    for (int mt = 0; mt < 3; ++mt) af[0][mt] = *(const f16x8*)(aB + (mt * 8 + 0) * 512);
#pragma unroll
    for (int nt = 0; nt < 2; ++nt) bf[0][nt] = *(const f16x8*)(bB + (nt * 8 + 0) * 512);

#pragma unroll
    for (int ks = 0; ks < 8; ++ks) {
        const int cur = ks & 1, nxt = cur ^ 1;
        if (ks < 7) {
#pragma unroll
            for (int mt = 0; mt < 3; ++mt)
                af[nxt][mt] = *(const f16x8*)(aB + (mt * 8 + ks + 1) * 512);
#pragma unroll
            for (int nt = 0; nt < 2; ++nt)
                bf[nxt][nt] = *(const f16x8*)(bB + (nt * 8 + ks + 1) * 512);
        }
#pragma unroll
        for (int mt = 0; mt < 3; ++mt)
#pragma unroll
            for (int nt = 0; nt < 2; ++nt)
                accv[mt * 2 + nt] = __builtin_amdgcn_mfma_f32_16x16x32_f16(af[cur][mt], bf[cur][nt], accv[mt * 2 + nt], 0, 0, 0);
    }
    // lane holds raw[r][w]: r = mt*16 + kg*4 + v, w = nt*16 + lm

    // ---- norm over w -> coef[r]; X cached in er[] for the exp pass ----
    f32x4 er[6];
    float coef[12];
#pragma unroll
    for (int mt = 0; mt < 3; ++mt)
#pragma unroll
        for (int v = 0; v < 4; ++v) {
            const int idx = mt * 4 + v;
            const float one_m = 1.f - mr[idx];
            float p = 0.f;
#pragma unroll
            for (int nt = 0; nt < 2; ++nt) {
                const float raw = accv[mt * 2 + nt][v];
                const float X = fmaxf(raw, 0.1f * raw) + one_m;   // leaky+pad
                er[mt * 2 + nt][v] = X;
                p += X * X;
            }
            p += __shfl_xor(p, 1);
            p += __shfl_xor(p, 2);
            p += __shfl_xor(p, 4);
            p += __shfl_xor(p, 8);
            coef[idx] = (LAMf * LOG2Ef) *
                        __builtin_amdgcn_rcpf(__builtin_amdgcn_sqrtf(p) + EPSf);
        }

    // ---- E = exp2(X*coef)*m; keep E in f32 regs AND LDS [w][72] f16 ----
    _Float16* sEw = &sE[wv][0];
    float den[2] = {0.f, 0.f}, Wv[2] = {0.f, 0.f};
#pragma unroll
    for (int nt = 0; nt < 2; ++nt) {
        const int w = nt * 16 + lm;
#pragma unroll
        for (int mt = 0; mt < 3; ++mt) {
            f16x4 pk;
#pragma unroll
            for (int v = 0; v < 4; ++v) {
                const int idx = mt * 4 + v;
                const float raw = accv[mt * 2 + nt][v];
                const float X   = er[mt * 2 + nt][v];
                const float E = __builtin_amdgcn_exp2f(X * coef[idx]) * mr[idx];
                er[mt * 2 + nt][v] = E;
                den[nt] += E;
                Wv[nt] += E * raw;
                pk[v] = (_Float16)E;
            }
            *(f16x4*)&sEw[w * 72 + mt * 16 + kg * 4] = pk;
        }
        // zero K-pad k = 48..63 (G kills it numerically, avoid stray NaN bits)
        f16x4 z4; z4[0] = z4[1] = z4[2] = z4[3] = (_Float16)0.f;
        *(f16x4*)&sEw[w * 72 + 48 + kg * 4] = z4;
    }
    // reduce den/W over kg (rows split across kg)
#pragma unroll
    for (int nt = 0; nt < 2; ++nt) {
        den[nt] += __shfl_xor(den[nt], 16);
        den[nt] += __shfl_xor(den[nt], 32);
        Wv[nt]  += __shfl_xor(Wv[nt], 16);
        Wv[nt]  += __shfl_xor(Wv[nt], 32);
    }

    // ---- n2: D = G(48x48) * E(48x32) -> C-layout aligned with er ----
    // accv reused as D (raw fully consumed above)
#pragma unroll
    for (int i = 0; i < 6; ++i) accv[i] = (f32x4){0.f, 0.f, 0.f, 0.f};
#pragma unroll
    for (int ks = 0; ks < 2; ++ks) {
        f16x8 ef[2], gf[3];
#pragma unroll
        for (int wt = 0; wt < 2; ++wt)
            ef[wt] = *(const f16x8*)&sEw[(wt * 16 + lm) * 72 + ks * 32 + kg * 8];
#pragma unroll
        for (int rt = 0; rt < 3; ++rt)
            gf[rt] = *(const f16x8*)(gB + (rt * 2 + ks) * 512);
#pragma unroll
        for (int rt = 0; rt < 3; ++rt)
#pragma unroll
            for (int wt = 0; wt < 2; ++wt)
                accv[rt * 2 + wt] = __builtin_amdgcn_mfma_f32_16x16x32_f16(gf[rt], ef[wt], accv[rt * 2 + wt], 0, 0, 0);
    }
    // n2[w] = sum_r D[r][w]*E[r][w]: pure register dot + kg reduction
    float n2v[2];
#pragma unroll
    for (int nt = 0; nt < 2; ++nt) {
        float p2 = 0.f;
#pragma unroll
        for (int rt = 0; rt < 3; ++rt)
#pragma unroll
            for (int v = 0; v < 4; ++v)
                p2 += accv[rt * 2 + nt][v] * er[rt * 2 + nt][v];
        p2 += __shfl_xor(p2, 16);
        p2 += __shfl_xor(p2, 32);
        n2v[nt] = p2;
    }

    // ---- final: cos (softmax denominators cancel), sum over words ----
    {
        float tot = 0.f;
#pragma unroll
        for (int nt = 0; nt < 2; ++nt) {
            const int w = nt * 16 + lm;
            const float n2 = fmaxf(n2v[nt], 0.f);
            const float denom = fmaxf(n1v[nt] * __builtin_amdgcn_sqrtf(n2), EPSf * den[nt]);
            const float cosv = Wv[nt] * __builtin_amdgcn_rcpf(denom);
            tot += (w < sl) ? cosv : 0.f;
        }
        tot += __shfl_xor(tot, 1);
        tot += __shfl_xor(tot, 2);
        tot += __shfl_xor(tot, 4);
        tot += __shfl_xor(tot, 8);
        if (lane == 0) ws[WS_SCORES + b * NB + c] = tot * __builtin_amdgcn_rcpf((float)sl);
    }
}

// ---------------- contrastive loss over 128x128 scores ----------------
__global__ __launch_bounds__(128) void loss_kernel(
    const float* __restrict__ scores, const int* __restrict__ qid,
    float* __restrict__ out)
{
    __shared__ int   s_q[NB];
    __shared__ float s_pa[2];
    __shared__ float s_pv[2];
    const int i = threadIdx.x;
    const int wvi = i >> 6, lane = i & 63;
    s_q[i] = qid[i];
    __syncthreads();

    const int q = s_q[i];
    bool dup = false;
    for (int j = 0; j < i; ++j) dup = dup || (s_q[j] == q);

    const float* row = scores + i * NB;
    float mx = -1e30f;
    for (int j = 0; j < NB; ++j) {
        float l = (row[j] - ((j == i) ? MARGINf : 0.f)) * TEMPf;
        mx = fmaxf(mx, l);
    }
    float sum = 0.f;
    for (int j = 0; j < NB; ++j) {
        float l = (row[j] - ((j == i) ? MARGINf : 0.f)) * TEMPf;
        sum += __builtin_amdgcn_exp2f((l - mx) * LOG2Ef);
    }
    const float logZ = mx + __builtin_amdgcn_logf(sum) * INV_LOG2Ef;
    const float picked = (row[i] - MARGINf) * TEMPf;
    const float valid = dup ? 0.f : 1.f;
    float a = (logZ - picked) * valid;
    float v = valid;
    // wave-parallel reduction, then combine the 2 waves through LDS
    a += __shfl_xor(a, 1);  v += __shfl_xor(v, 1);
    a += __shfl_xor(a, 2);  v += __shfl_xor(v, 2);
    a += __shfl_xor(a, 4);  v += __shfl_xor(v, 4);
    a += __shfl_xor(a, 8);  v += __shfl_xor(v, 8);
    a += __shfl_xor(a, 16); v += __shfl_xor(v, 16);
    a += __shfl_xor(a, 32); v += __shfl_xor(v, 32);
    if (lane == 0) { s_pa[wvi] = a; s_pv[wvi] = v; }
    __syncthreads();
    if (i == 0)
        out[0] = (s_pa[0] + s_pa[1]) / fmaxf(s_pv[0] + s_pv[1], 1.f);
}

extern "C" void kernel_launch(void* const* d_in, const int* in_sizes, int n_in,
                              void* d_out, int out_size, void* d_ws, size_t ws_size,
                              hipStream_t stream) {
    const float* im      = (const float*)d_in[0];
    const float* s       = (const float*)d_in[1];
    const int*   s_l     = (const int*)d_in[2];
    const float* im_mask = (const float*)d_in[3];
    const int*   qid     = (const int*)d_in[4];

    float* ws  = (float*)d_ws;
    float* out = (float*)d_out;

    prep5_kernel<<<2 * NB, 256, 0, stream>>>(im, s, s_l, ws);
    wavefused11_kernel<<<dim3(32, NB), 256, 0, stream>>>(s_l, im_mask, ws);
    loss_kernel<<<1, 128, 0, stream>>>(ws + WS_SCORES, qid, out);
}

// Round 9
// 126.486 us; speedup vs baseline: 1.6601x; 1.0174x over previous
//
#include <hip/hip_runtime.h>
#include <hip/hip_bf16.h>
#include <math.h>

#define NB 128   // batch
#define NR 36    // regions
#define NW 32    // words
#define ND 256   // feature dim

#define MARGINf 0.05f
#define TEMPf   14.0f
#define LAMf    9.0f
#define EPSf    1e-8f
#define LOG2Ef  1.4426950408889634f
#define INV_LOG2Ef 0.6931471805599453f

typedef _Float16 f16x8 __attribute__((ext_vector_type(8)));
typedef _Float16 f16x4 __attribute__((ext_vector_type(4)));
typedef float    f32x4 __attribute__((ext_vector_type(4)));

// ================= workspace layout (float offsets) =================
// All GEMM operands stored in MFMA-fragment order ("swizzled"):
//   fragment f, lane l, elem j  ->  base + f*512 + l*8 + j   (halves)
// so a wave's f16x8 fragment load = 64 lanes x 16B contiguous = 1KB burst.
#define WS_SCORES 0
#define WS_N1     16384
#define WS_GW     20480                   // f16[128][6*512]   (rt*2+ks frags)
#define GW_H      3072
#define WS_IMW    217088                  // f16[128][24*512]  (mt*8+ks frags)
#define IMW_H     12288
#define WS_SHW    1003520                 // f16[128][16*512]  (nt*8+ks frags)
#define SHW_H     8192

// =====================================================================
// prep5 (R2, unchanged): im-side blocks (b < NB) and s-side (b >= NB).
// =====================================================================
__global__ __launch_bounds__(256) void prep5_kernel(
    const float* __restrict__ im, const float* __restrict__ s,
    const int* __restrict__ s_l, float* __restrict__ ws)
{
    const int t = threadIdx.x;
    const int bid = blockIdx.x;

    __shared__ __align__(16) float    s_imf[NR * 260];
    __shared__ __align__(16) _Float16 s_frag[24 * 512];   // imw fragments, 24KB
    __shared__ __align__(16) _Float16 s_G[48 * 72];

    if (bid < NB) {
        // ================= im-side =================
        const int b = bid;
        const float4* im4 = (const float4*)(im + (size_t)b * NR * ND);
        for (int i = t; i < NR * 64; i += 256) {
            int r = i >> 6, c4 = i & 63;
            *(float4*)&s_imf[r * 260 + 4 * c4] = im4[i];
        }
        // zero G LDS (1728 u32) — MFMA only fills cols 0..47; pad stays 0
        for (int i = t; i < 1728; i += 256) ((unsigned int*)s_G)[i] = 0u;
        __syncthreads();

        // imw swizzled: 24 fragments (mt*8+ks) x 64 lanes, rows >=36 zero.
        // Write to global AND stage in LDS for the Gram MFMA.
        _Float16* imw = (_Float16*)(ws + WS_IMW) + (size_t)b * IMW_H;
        for (int i = t; i < 24 * 64; i += 256) {
            const int f = i >> 6, l = i & 63;
            const int mt = f >> 3, ks = f & 7;
            const int lmi = l & 15, kgi = l >> 4;
            const int r = mt * 16 + lmi;
            f16x8 h;
            if (r < NR) {
                const int k0 = ks * 32 + kgi * 8;
                const float4 a  = *(const float4*)&s_imf[r * 260 + k0];
                const float4 bb = *(const float4*)&s_imf[r * 260 + k0 + 4];
                h[0] = (_Float16)a.x;  h[1] = (_Float16)a.y;
                h[2] = (_Float16)a.z;  h[3] = (_Float16)a.w;
                h[4] = (_Float16)bb.x; h[5] = (_Float16)bb.y;
                h[6] = (_Float16)bb.z; h[7] = (_Float16)bb.w;
            } else {
#pragma unroll
                for (int k = 0; k < 8; ++k) h[k] = (_Float16)0.f;
            }
            *(f16x8*)(imw + f * 512 + l * 8) = h;
            *(f16x8*)(s_frag + f * 512 + l * 8) = h;
        }
        __syncthreads();

        // Gram via MFMA: G[i][j] = im[i].im[j], tiles (ta,tb) in 16x16,
        // K=256 over 8 fragment k-slices. Pair p = ta*3+tb, 9 pairs over
        // 4 waves. mfma(rowfragA, rowfragB) -> C[i=kg*4+v][j=lm] = A_i . B_j.
        {
            const int wv = t >> 6, lane = t & 63;
            const int lmi = lane & 15, kgi = lane >> 4;
            for (int p = wv; p < 9; p += 4) {
                const int ta = p / 3, tb = p - ta * 3;
                f32x4 acc = (f32x4){0.f, 0.f, 0.f, 0.f};
#pragma unroll
                for (int ks = 0; ks < 8; ++ks) {
                    f16x8 a  = *(const f16x8*)(s_frag + (ta * 8 + ks) * 512 + lane * 8);
                    f16x8 bb = *(const f16x8*)(s_frag + (tb * 8 + ks) * 512 + lane * 8);
                    acc = __builtin_amdgcn_mfma_f32_16x16x32_f16(a, bb, acc, 0, 0, 0);
                }
#pragma unroll
                for (int v = 0; v < 4; ++v) {
                    const int row = ta * 16 + kgi * 4 + v;
                    s_G[row * 72 + tb * 16 + lmi] = (_Float16)acc[v];
                }
            }
        }
        __syncthreads();

        // Gw swizzled: 6 fragments (rt*2+ks) x 64 lanes
        _Float16* Gw = (_Float16*)(ws + WS_GW) + (size_t)b * GW_H;
        for (int i = t; i < 6 * 64; i += 256) {
            const int f = i >> 6, l = i & 63;
            const int rt = f >> 1, ks = f & 1;
            const int lmi = l & 15, kgi = l >> 4;
            f16x8 h = *(const f16x8*)&s_G[(rt * 16 + lmi) * 72 + ks * 32 + kgi * 8];
            *(f16x8*)((_Float16*)Gw + f * 512 + l * 8) = h;
        }
    } else {
        // ================= s-side =================
        const int b = bid - NB;
        const int sl = s_l[b];
        _Float16* shw = (_Float16*)(ws + WS_SHW) + (size_t)b * SHW_H;
        const float4* s4 = (const float4*)(s + (size_t)b * NW * ND);

        // shw swizzled: 16 fragments (nt*8+ks) x 64 lanes, word-masked
        for (int i = t; i < 16 * 64; i += 256) {
            const int f = i >> 6, l = i & 63;
            const int nt = f >> 3, ks = f & 7;
            const int lmi = l & 15, kgi = l >> 4;
            const int w = nt * 16 + lmi;
            f16x8 h;
            if (w < sl) {
                const int k0 = ks * 32 + kgi * 8;     // multiple of 8 floats
                const float4 a  = s4[w * 64 + (k0 >> 2)];
                const float4 bb = s4[w * 64 + (k0 >> 2) + 1];
                h[0] = (_Float16)a.x;  h[1] = (_Float16)a.y;
                h[2] = (_Float16)a.z;  h[3] = (_Float16)a.w;
                h[4] = (_Float16)bb.x; h[5] = (_Float16)bb.y;
                h[6] = (_Float16)bb.z; h[7] = (_Float16)bb.w;
            } else {
#pragma unroll
                for (int k = 0; k < 8; ++k) h[k] = (_Float16)0.f;
            }
            *(f16x8*)(shw + f * 512 + l * 8) = h;
        }

        // n1[b][w]
        {
            const int w = t >> 3, g = t & 7;
            float acc = 0.f;
            for (int j = 0; j < 8; ++j) {
                float4 v = s4[w * 64 + g * 8 + j];
                acc += v.x * v.x + v.y * v.y + v.z * v.z + v.w * v.w;
            }
            acc += __shfl_down(acc, 4, 8);
            acc += __shfl_down(acc, 2, 8);
            acc += __shfl_down(acc, 1, 8);
            if (g == 0) ws[WS_N1 + b * NW + w] = sqrtf(acc);
        }
    }
}

// =====================================================================
// wavefused12: BYTE-EXACT R2 wavefused5 body + XCD-locality tile remap.
// Only the (b,c) derivation changed (4 integer ops at entry):
//   g = linear block id; xcd = g&7 (HW round-robins blocks over XCDs);
//   each XCD owns a fixed 16-caption B-panel (256KB, stays L2-resident)
//   and walks b with 4 consecutive blocks per b (A(b) 24KB hot window).
// Steady-state per-XCD L2 working set ~280KB vs ~5MB with the old map
// (measured 19.7MB FETCH = 3.4x unique operands). Bijection: (b,cg) <->
// g via xcd=cg>>2, idx=(b<<2)|(cg&3), g=(idx<<3)|xcd. Body untouched.
// =====================================================================
__global__ __launch_bounds__(256, 4) void wavefused12_kernel(
    const int* __restrict__ s_l, const float* __restrict__ im_mask,
    float* __restrict__ ws)
{
    const int t = threadIdx.x;
    const int wv = t >> 6, lane = t & 63;
    const int lm = lane & 15, kg = lane >> 4;

    // ---- XCD-locality remap (replaces b=blockIdx.y, c=blockIdx.x*4+wv) ----
    const int g   = blockIdx.y * 32 + blockIdx.x;   // linear dispatch id
    const int xcd = g & 7;
    const int idx = g >> 3;
    const int b   = idx >> 2;
    const int c   = (xcd * 4 + (idx & 3)) * 4 + wv;

    __shared__ _Float16 sE[4][32 * 72];   // per-wave E tile [w][k], 4.6 KB each

    const _Float16* aB = (const _Float16*)(ws + WS_IMW) + (size_t)b * IMW_H + lane * 8;
    const _Float16* bB = (const _Float16*)(ws + WS_SHW) + (size_t)c * SHW_H + lane * 8;
    const _Float16* gB = (const _Float16*)(ws + WS_GW) + (size_t)b * GW_H + lane * 8;

    // early small loads (L1/L2-resident, broadcast-friendly)
    float n1v[2];
#pragma unroll
    for (int nt = 0; nt < 2; ++nt)
        n1v[nt] = ws[WS_N1 + c * NW + nt * 16 + lm];
    float mr[12];
#pragma unroll
    for (int mt = 0; mt < 3; ++mt)
#pragma unroll
        for (int v = 0; v < 4; ++v) {
            const int r = mt * 16 + kg * 4 + v;
            mr[mt * 4 + v] = (r < NR) ? im_mask[b * NR + r] : 0.f;
        }
    const int sl = s_l[c];

    // accumulator array, aliased:
    //   phase 1: accv[mt*2+nt] = A0 raw tile
    //   n2 MFMA: accv[rt*2+wt] = D tile (raw dead by then)
    f32x4 accv[6];
#pragma unroll
    for (int i = 0; i < 6; ++i) accv[i] = (f32x4){0.f, 0.f, 0.f, 0.f};

    // ---- phase 1: A0 tile 48(r) x 32(w), K=256, coalesced frag loads ----
    f16x8 af[2][3], bf[2][2];
#pragma unroll
    for (int mt = 0; mt < 3; ++mt) af[0][mt] = *(const f16x8*)(aB + (mt * 8 + 0) * 512);
#pragma unroll
    for (int nt = 0; nt < 2; ++nt) bf[0][nt] = *(const f16x8*)(bB + (nt * 8 + 0) * 512);

#pragma unroll
    for (int ks = 0; ks < 8; ++ks) {
        const int cur = ks & 1, nxt = cur ^ 1;
        if (ks < 7) {
#pragma unroll
            for (int mt = 0; mt < 3; ++mt)
                af[nxt][mt] = *(const f16x8*)(aB + (mt * 8 + ks + 1) * 512);
#pragma unroll
            for (int nt = 0; nt < 2; ++nt)
                bf[nxt][nt] = *(const f16x8*)(bB + (nt * 8 + ks + 1) * 512);
        }
#pragma unroll
        for (int mt = 0; mt < 3; ++mt)
#pragma unroll
            for (int nt = 0; nt < 2; ++nt)
                accv[mt * 2 + nt] = __builtin_amdgcn_mfma_f32_16x16x32_f16(af[cur][mt], bf[cur][nt], accv[mt * 2 + nt], 0, 0, 0);
    }
    // lane holds raw[r][w]: r = mt*16 + kg*4 + v, w = nt*16 + lm

    // ---- norm over w -> coef[r]; X cached in er[] for the exp pass ----
    f32x4 er[6];
    float coef[12];
#pragma unroll
    for (int mt = 0; mt < 3; ++mt)
#pragma unroll
        for (int v = 0; v < 4; ++v) {
            const int idx2 = mt * 4 + v;
            const float one_m = 1.f - mr[idx2];
            float p = 0.f;
#pragma unroll
            for (int nt = 0; nt < 2; ++nt) {
                const float raw = accv[mt * 2 + nt][v];
                const float X = fmaxf(raw, 0.1f * raw) + one_m;   // leaky+pad
                er[mt * 2 + nt][v] = X;
                p += X * X;
            }
            p += __shfl_xor(p, 1);
            p += __shfl_xor(p, 2);
            p += __shfl_xor(p, 4);
            p += __shfl_xor(p, 8);
            coef[idx2] = (LAMf * LOG2Ef) *
                        __builtin_amdgcn_rcpf(__builtin_amdgcn_sqrtf(p) + EPSf);
        }

    // ---- E = exp2(X*coef)*m; keep E in f32 regs AND LDS [w][72] f16 ----
    _Float16* sEw = &sE[wv][0];
    float den[2] = {0.f, 0.f}, Wv[2] = {0.f, 0.f};
#pragma unroll
    for (int nt = 0; nt < 2; ++nt) {
        const int w = nt * 16 + lm;
#pragma unroll
        for (int mt = 0; mt < 3; ++mt) {
            f16x4 pk;
#pragma unroll
            for (int v = 0; v < 4; ++v) {
                const int idx2 = mt * 4 + v;
                const float raw = accv[mt * 2 + nt][v];
                const float X   = er[mt * 2 + nt][v];
                const float E = __builtin_amdgcn_exp2f(X * coef[idx2]) * mr[idx2];
                er[mt * 2 + nt][v] = E;
                den[nt] += E;
                Wv[nt] += E * raw;
                pk[v] = (_Float16)E;
            }
            *(f16x4*)&sEw[w * 72 + mt * 16 + kg * 4] = pk;
        }
        // zero K-pad k = 48..63 (G kills it numerically, avoid stray NaN bits)
        f16x4 z4; z4[0] = z4[1] = z4[2] = z4[3] = (_Float16)0.f;
        *(f16x4*)&sEw[w * 72 + 48 + kg * 4] = z4;
    }
    // reduce den/W over kg (rows split across kg)
#pragma unroll
    for (int nt = 0; nt < 2; ++nt) {
        den[nt] += __shfl_xor(den[nt], 16);
        den[nt] += __shfl_xor(den[nt], 32);
        Wv[nt]  += __shfl_xor(Wv[nt], 16);
        Wv[nt]  += __shfl_xor(Wv[nt], 32);
    }

    // ---- n2: D = G(48x48) * E(48x32) -> C-layout aligned with er ----
    // accv reused as D (raw fully consumed above)
#pragma unroll
    for (int i = 0; i < 6; ++i) accv[i] = (f32x4){0.f, 0.f, 0.f, 0.f};
#pragma unroll
    for (int ks = 0; ks < 2; ++ks) {
        f16x8 ef[2], gf[3];
#pragma unroll
        for (int wt = 0; wt < 2; ++wt)
            ef[wt] = *(const f16x8*)&sEw[(wt * 16 + lm) * 72 + ks * 32 + kg * 8];
#pragma unroll
        for (int rt = 0; rt < 3; ++rt)
            gf[rt] = *(const f16x8*)(gB + (rt * 2 + ks) * 512);
#pragma unroll
        for (int rt = 0; rt < 3; ++rt)
#pragma unroll
            for (int wt = 0; wt < 2; ++wt)
                accv[rt * 2 + wt] = __builtin_amdgcn_mfma_f32_16x16x32_f16(gf[rt], ef[wt], accv[rt * 2 + wt], 0, 0, 0);
    }
    // n2[w] = sum_r D[r][w]*E[r][w]: pure register dot + kg reduction
    float n2v[2];
#pragma unroll
    for (int nt = 0; nt < 2; ++nt) {
        float p2 = 0.f;
#pragma unroll
        for (int rt = 0; rt < 3; ++rt)
#pragma unroll
            for (int v = 0; v < 4; ++v)
                p2 += accv[rt * 2 + nt][v] * er[rt * 2 + nt][v];
        p2 += __shfl_xor(p2, 16);
        p2 += __shfl_xor(p2, 32);
        n2v[nt] = p2;
    }

    // ---- final: cos (softmax denominators cancel), sum over words ----
    {
        float tot = 0.f;
#pragma unroll
        for (int nt = 0; nt < 2; ++nt) {
            const int w = nt * 16 + lm;
            const float n2 = fmaxf(n2v[nt], 0.f);
            const float denom = fmaxf(n1v[nt] * __builtin_amdgcn_sqrtf(n2), EPSf * den[nt]);
            const float cosv = Wv[nt] * __builtin_amdgcn_rcpf(denom);
            tot += (w < sl) ? cosv : 0.f;
        }
        tot += __shfl_xor(tot, 1);
        tot += __shfl_xor(tot, 2);
        tot += __shfl_xor(tot, 4);
        tot += __shfl_xor(tot, 8);
        if (lane == 0) ws[WS_SCORES + b * NB + c] = tot * __builtin_amdgcn_rcpf((float)sl);
    }
}

// ---------------- contrastive loss over 128x128 scores ----------------
__global__ __launch_bounds__(128) void loss_kernel(
    const float* __restrict__ scores, const int* __restrict__ qid,
    float* __restrict__ out)
{
    __shared__ int   s_q[NB];
    __shared__ float s_pa[2];
    __shared__ float s_pv[2];
    const int i = threadIdx.x;
    const int wvi = i >> 6, lane = i & 63;
    s_q[i] = qid[i];
    __syncthreads();

    const int q = s_q[i];
    bool dup = false;
    for (int j = 0; j < i; ++j) dup = dup || (s_q[j] == q);

    const float* row = scores + i * NB;
    float mx = -1e30f;
    for (int j = 0; j < NB; ++j) {
        float l = (row[j] - ((j == i) ? MARGINf : 0.f)) * TEMPf;
        mx = fmaxf(mx, l);
    }
    float sum = 0.f;
    for (int j = 0; j < NB; ++j) {
        float l = (row[j] - ((j == i) ? MARGINf : 0.f)) * TEMPf;
        sum += __builtin_amdgcn_exp2f((l - mx) * LOG2Ef);
    }
    const float logZ = mx + __builtin_amdgcn_logf(sum) * INV_LOG2Ef;
    const float picked = (row[i] - MARGINf) * TEMPf;
    const float valid = dup ? 0.f : 1.f;
    float a = (logZ - picked) * valid;
    float v = valid;
    // wave-parallel reduction, then combine the 2 waves through LDS
    a += __shfl_xor(a, 1);  v += __shfl_xor(v, 1);
    a += __shfl_xor(a, 2);  v += __shfl_xor(v, 2);
    a += __shfl_xor(a, 4);  v += __shfl_xor(v, 4);
    a += __shfl_xor(a, 8);  v += __shfl_xor(v, 8);
    a += __shfl_xor(a, 16); v += __shfl_xor(v, 16);
    a += __shfl_xor(a, 32); v += __shfl_xor(v, 32);
    if (lane == 0) { s_pa[wvi] = a; s_pv[wvi] = v; }
    __syncthreads();
    if (i == 0)
        out[0] = (s_pa[0] + s_pa[1]) / fmaxf(s_pv[0] + s_pv[1], 1.f);
}

extern "C" void kernel_launch(void* const* d_in, const int* in_sizes, int n_in,
                              void* d_out, int out_size, void* d_ws, size_t ws_size,
                              hipStream_t stream) {
    const float* im      = (const float*)d_in[0];
    const float* s       = (const float*)d_in[1];
    const int*   s_l     = (const int*)d_in[2];
    const float* im_mask = (const float*)d_in[3];
    const int*   qid     = (const int*)d_in[4];

    float* ws  = (float*)d_ws;
    float* out = (float*)d_out;

    prep5_kernel<<<2 * NB, 256, 0, stream>>>(im, s, s_l, ws);
    wavefused12_kernel<<<dim3(32, NB), 256, 0, stream>>>(s_l, im_mask, ws);
    loss_kernel<<<1, 128, 0, stream>>>(ws + WS_SCORES, qid, out);
}